// Round 8
// baseline (1081.139 us; speedup 1.0000x reference)
//
#include <hip/hip_runtime.h>
#include <hip/hip_bf16.h>

// AliNetGraphAttentionLayer: N=100000, E=1600000, D_IN=256, D_OUT=128
// Dtype model v5 (final, fits ALL rounds + documented contract):
//   ALL float inputs f32 (R7 detector: no flags tripped, R7 ≡ R2/R5 bit-exact;
//   R1/R6 bf16 reads -> NaN from f32 low half-words). OUTPUT f32 per contract
//   ("reference's OUTPUT dtype ... else float*"; reference returns float32).
//   R2/R5/R7's 3.06 = bf16-u16 pairs packed into an f32 buffer (flat[i] ~
//   out[2i+1], second half zeros). R3 (f32 out, correct) aborted due to the
//   same infra flakiness that killed R4's container twice.
#define D_IN 256
#define D_OUT 128
#define EPS_BN 1e-3f
#define LEAKY 0.2f

typedef unsigned short u16;
typedef unsigned int u32;

__device__ __forceinline__ float bf2f(u16 u) {
    u32 v = ((u32)u) << 16;
    return __uint_as_float(v);
}
__device__ __forceinline__ u16 f2bf(float f) {
    u32 u = __float_as_uint(f);
    u32 r = (u + 0x7FFFu + ((u >> 16) & 1u)) >> 16;  // RNE
    return (u16)r;
}

// ---------------- column stats ----------------
__global__ void colstats_k(const float* __restrict__ x, int n,
                           float* __restrict__ sums, float* __restrict__ sqs) {
    int c = threadIdx.x;
    float s = 0.f, q = 0.f;
    for (int r = blockIdx.x; r < n; r += gridDim.x) {
        float v = x[(size_t)r * D_IN + c];
        s += v;
        q += v * v;
    }
    atomicAdd(&sums[c], s);
    atomicAdd(&sqs[c], q);
}

__global__ void finalize_k(const float* __restrict__ sums, const float* __restrict__ sqs,
                           int n, float* __restrict__ mean, float* __restrict__ inv) {
    int c = threadIdx.x;
    float m = sums[c] / (float)n;
    float v = sqs[c] / (float)n - m * m;
    mean[c] = m;
    inv[c] = rsqrtf(v + EPS_BN);
}

// ---------------- BN + quadratic form: out[m] = tanh(rowsum((xn@B).*xn)) ----------------
__global__ __launch_bounds__(256) void gemm_quad_k(const float* __restrict__ x,
                                                   const float* __restrict__ B,
                                                   const float* __restrict__ mean,
                                                   const float* __restrict__ inv,
                                                   float* __restrict__ outp, int n) {
    __shared__ float As[64][68];
    __shared__ float Bs[64][68];
    const int tid = threadIdx.x;
    const int tx = tid & 15, ty = tid >> 4;
    const int m0 = blockIdx.x * 64;
    float s_acc[4] = {0.f, 0.f, 0.f, 0.f};

    for (int jt = 0; jt < D_IN; jt += 64) {
        float acc[4][4];
#pragma unroll
        for (int a = 0; a < 4; ++a)
#pragma unroll
            for (int b = 0; b < 4; ++b) acc[a][b] = 0.f;

        for (int kt = 0; kt < D_IN; kt += 64) {
#pragma unroll
            for (int i = 0; i < 4; ++i) {
                int f4 = tid + 256 * i;
                int r = f4 >> 4;
                int c4 = (f4 & 15) << 2;
                float4 o;
                int gr = m0 + r;
                if (gr < n) {
                    float4 v = *(const float4*)(x + (size_t)gr * D_IN + kt + c4);
                    float4 mn = *(const float4*)(mean + kt + c4);
                    float4 iv = *(const float4*)(inv + kt + c4);
                    o.x = (v.x - mn.x) * iv.x;
                    o.y = (v.y - mn.y) * iv.y;
                    o.z = (v.z - mn.z) * iv.z;
                    o.w = (v.w - mn.w) * iv.w;
                } else {
                    o = make_float4(0.f, 0.f, 0.f, 0.f);
                }
                *(float4*)&As[r][c4] = o;
            }
#pragma unroll
            for (int i = 0; i < 4; ++i) {
                int f4 = tid + 256 * i;
                int r = f4 >> 4;
                int c4 = (f4 & 15) << 2;
                *(float4*)&Bs[r][c4] =
                    *(const float4*)(B + (size_t)(kt + r) * D_IN + jt + c4);
            }
            __syncthreads();
#pragma unroll 8
            for (int k = 0; k < 64; ++k) {
                float4 bv = *(const float4*)&Bs[k][tx << 2];
                float a0 = As[(ty << 2) + 0][k];
                float a1 = As[(ty << 2) + 1][k];
                float a2 = As[(ty << 2) + 2][k];
                float a3 = As[(ty << 2) + 3][k];
                acc[0][0] = fmaf(a0, bv.x, acc[0][0]);
                acc[0][1] = fmaf(a0, bv.y, acc[0][1]);
                acc[0][2] = fmaf(a0, bv.z, acc[0][2]);
                acc[0][3] = fmaf(a0, bv.w, acc[0][3]);
                acc[1][0] = fmaf(a1, bv.x, acc[1][0]);
                acc[1][1] = fmaf(a1, bv.y, acc[1][1]);
                acc[1][2] = fmaf(a1, bv.z, acc[1][2]);
                acc[1][3] = fmaf(a1, bv.w, acc[1][3]);
                acc[2][0] = fmaf(a2, bv.x, acc[2][0]);
                acc[2][1] = fmaf(a2, bv.y, acc[2][1]);
                acc[2][2] = fmaf(a2, bv.z, acc[2][2]);
                acc[2][3] = fmaf(a2, bv.w, acc[2][3]);
                acc[3][0] = fmaf(a3, bv.x, acc[3][0]);
                acc[3][1] = fmaf(a3, bv.y, acc[3][1]);
                acc[3][2] = fmaf(a3, bv.z, acc[3][2]);
                acc[3][3] = fmaf(a3, bv.w, acc[3][3]);
            }
            __syncthreads();
        }
#pragma unroll
        for (int a = 0; a < 4; ++a) {
            int gm = m0 + (ty << 2) + a;
            if (gm < n) {
                int c = jt + (tx << 2);
                float4 v = *(const float4*)(x + (size_t)gm * D_IN + c);
                float4 mn = *(const float4*)(mean + c);
                float4 iv = *(const float4*)(inv + c);
                s_acc[a] += acc[a][0] * (v.x - mn.x) * iv.x +
                            acc[a][1] * (v.y - mn.y) * iv.y +
                            acc[a][2] * (v.z - mn.z) * iv.z +
                            acc[a][3] * (v.w - mn.w) * iv.w;
            }
        }
    }
#pragma unroll
    for (int a = 0; a < 4; ++a) {
        float v = s_acc[a];
        v += __shfl_xor(v, 1);
        v += __shfl_xor(v, 2);
        v += __shfl_xor(v, 4);
        v += __shfl_xor(v, 8);
        if (tx == 0) {
            int gm = m0 + (ty << 2) + a;
            if (gm < n) outp[gm] = tanhf(v);
        }
    }
}

// ---------------- BN + mapped GEMM for column tile [c0, c0+CT) ----------------
// OT = float or u16 (bf16 ws fallback). CT | 128, c0 multiple of CT.
template <typename OT>
__global__ __launch_bounds__(256) void gemm_map_k(const float* __restrict__ x,
                                                  const float* __restrict__ w,
                                                  const float* __restrict__ mean,
                                                  const float* __restrict__ inv,
                                                  OT* __restrict__ outp, int n,
                                                  int c0, int CT) {
    __shared__ float As[64][68];
    __shared__ float Bs[64][68];
    const int tid = threadIdx.x;
    const int tx = tid & 15, ty = tid >> 4;
    const int m0 = blockIdx.x * 64;
    const int tiles = (CT + 63) >> 6;  // 1 or 2

    for (int t = 0; t < tiles; ++t) {
        const int jt = c0 + (t << 6);
        float acc[4][4];
#pragma unroll
        for (int a = 0; a < 4; ++a)
#pragma unroll
            for (int b = 0; b < 4; ++b) acc[a][b] = 0.f;

        for (int kt = 0; kt < D_IN; kt += 64) {
#pragma unroll
            for (int i = 0; i < 4; ++i) {
                int f4 = tid + 256 * i;
                int r = f4 >> 4;
                int c4 = (f4 & 15) << 2;
                float4 o;
                int gr = m0 + r;
                if (gr < n) {
                    float4 v = *(const float4*)(x + (size_t)gr * D_IN + kt + c4);
                    float4 mn = *(const float4*)(mean + kt + c4);
                    float4 iv = *(const float4*)(inv + kt + c4);
                    o.x = (v.x - mn.x) * iv.x;
                    o.y = (v.y - mn.y) * iv.y;
                    o.z = (v.z - mn.z) * iv.z;
                    o.w = (v.w - mn.w) * iv.w;
                } else {
                    o = make_float4(0.f, 0.f, 0.f, 0.f);
                }
                *(float4*)&As[r][c4] = o;
            }
#pragma unroll
            for (int i = 0; i < 4; ++i) {
                int f4 = tid + 256 * i;
                int r = f4 >> 4;
                int c4 = (f4 & 15) << 2;
                int jc = jt + c4;
                float4 bv = (jc < D_OUT)
                                ? *(const float4*)(w + (size_t)(kt + r) * D_OUT + jc)
                                : make_float4(0.f, 0.f, 0.f, 0.f);
                *(float4*)&Bs[r][c4] = bv;
            }
            __syncthreads();
#pragma unroll 8
            for (int k = 0; k < 64; ++k) {
                float4 bv = *(const float4*)&Bs[k][tx << 2];
                float a0 = As[(ty << 2) + 0][k];
                float a1 = As[(ty << 2) + 1][k];
                float a2 = As[(ty << 2) + 2][k];
                float a3 = As[(ty << 2) + 3][k];
                acc[0][0] = fmaf(a0, bv.x, acc[0][0]);
                acc[0][1] = fmaf(a0, bv.y, acc[0][1]);
                acc[0][2] = fmaf(a0, bv.z, acc[0][2]);
                acc[0][3] = fmaf(a0, bv.w, acc[0][3]);
                acc[1][0] = fmaf(a1, bv.x, acc[1][0]);
                acc[1][1] = fmaf(a1, bv.y, acc[1][1]);
                acc[1][2] = fmaf(a1, bv.z, acc[1][2]);
                acc[1][3] = fmaf(a1, bv.w, acc[1][3]);
                acc[2][0] = fmaf(a2, bv.x, acc[2][0]);
                acc[2][1] = fmaf(a2, bv.y, acc[2][1]);
                acc[2][2] = fmaf(a2, bv.z, acc[2][2]);
                acc[2][3] = fmaf(a2, bv.w, acc[2][3]);
                acc[3][0] = fmaf(a3, bv.x, acc[3][0]);
                acc[3][1] = fmaf(a3, bv.y, acc[3][1]);
                acc[3][2] = fmaf(a3, bv.z, acc[3][2]);
                acc[3][3] = fmaf(a3, bv.w, acc[3][3]);
            }
            __syncthreads();
        }
        int si = (jt - c0) + (tx << 2);
        if (si < CT) {
#pragma unroll
            for (int a = 0; a < 4; ++a) {
                int gm = m0 + (ty << 2) + a;
                if (gm < n) {
                    if constexpr (sizeof(OT) == 4) {
                        *(float4*)((float*)outp + (size_t)gm * CT + si) =
                            make_float4(acc[a][0], acc[a][1], acc[a][2], acc[a][3]);
                    } else {
                        ushort4 pk;
                        pk.x = f2bf(acc[a][0]);
                        pk.y = f2bf(acc[a][1]);
                        pk.z = f2bf(acc[a][2]);
                        pk.w = f2bf(acc[a][3]);
                        *(ushort4*)((u16*)outp + (size_t)gm * CT + si) = pk;
                    }
                }
            }
        }
    }
}

// ---------------- CSR row_ptr from sorted rows ----------------
__global__ void build_rowptr_k(const int* __restrict__ rows, int E, int n,
                               int* __restrict__ rp) {
    int e = blockIdx.x * blockDim.x + threadIdx.x;
    if (e >= E) return;
    int r = rows[e];
    int prev = (e == 0) ? -1 : rows[e - 1];
    for (int q = prev + 1; q <= r; ++q) rp[q] = e;
    if (e == E - 1) {
        for (int q = r + 1; q <= n; ++q) rp[q] = E;
    }
}

// ---------------- per-row softmax stats (max, 1/denom) [+ alpha] ----------------
template <bool WRITE_ALPHA>
__global__ __launch_bounds__(256) void row_softmax_k(
    const int* __restrict__ row_ptr, const int* __restrict__ cols,
    const float* __restrict__ ev, const float* __restrict__ s1,
    const float* __restrict__ s2, float* __restrict__ rmax,
    float* __restrict__ rsm, float* __restrict__ alpha, int n) {
    int wave = threadIdx.x >> 6;
    int lane = threadIdx.x & 63;
    int row = blockIdx.x * 4 + wave;
    if (row >= n) return;
    int e0 = row_ptr[row], e1 = row_ptr[row + 1];
    if (e0 >= e1) {
        if (lane == 0) {
            rmax[row] = 0.f;
            rsm[row] = 0.f;
        }
        return;
    }
    float s1r = s1[row];
    float mx = -1e30f;
    for (int e = e0 + lane; e < e1; e += 64) {
        float v = ev[e] * (s1r + s2[cols[e]]);
        v = v > 0.f ? v : LEAKY * v;
        mx = fmaxf(mx, v);
    }
#pragma unroll
    for (int off = 32; off; off >>= 1) mx = fmaxf(mx, __shfl_xor(mx, off));
    float sm = 0.f;
    for (int e = e0 + lane; e < e1; e += 64) {
        float v = ev[e] * (s1r + s2[cols[e]]);
        v = v > 0.f ? v : LEAKY * v;
        sm += __expf(v - mx);
    }
#pragma unroll
    for (int off = 32; off; off >>= 1) sm += __shfl_xor(sm, off);
    float rsm_v = 1.f / sm;
    if (lane == 0) {
        rmax[row] = mx;
        rsm[row] = rsm_v;
    }
    if constexpr (WRITE_ALPHA) {
        for (int e = e0 + lane; e < e1; e += 64) {
            float v = ev[e] * (s1r + s2[cols[e]]);
            v = v > 0.f ? v : LEAKY * v;
            alpha[e] = __expf(v - mx) * rsm_v;
        }
    }
}

// ---------------- gather: out[row][c0..c0+CT) = sum_e alpha_e * mapped[col_e] ----------------
template <typename MT, bool HAS_ALPHA>
__global__ __launch_bounds__(256) void attn_gather_k(
    const int* __restrict__ row_ptr, const int* __restrict__ cols,
    const float* __restrict__ alpha, const float* __restrict__ ev,
    const float* __restrict__ s1, const float* __restrict__ s2,
    const float* __restrict__ rmax, const float* __restrict__ rsm,
    const MT* __restrict__ mapped, float* __restrict__ outp, int n, int c0, int CT) {
    int wave = threadIdx.x >> 6;
    int lane = threadIdx.x & 63;
    int row = blockIdx.x * 4 + wave;
    if (row >= n) return;
    int e0 = row_ptr[row], e1 = row_ptr[row + 1];
    float* orow = outp + (size_t)row * D_OUT + c0;
    if (e0 >= e1) {
        if (lane < CT) orow[lane] = 0.f;
        if (lane + 64 < CT) orow[lane + 64] = 0.f;
        return;
    }
    float s1r = 0.f, mxv = 0.f, rsv = 0.f;
    if constexpr (!HAS_ALPHA) {
        s1r = s1[row];
        mxv = rmax[row];
        rsv = rsm[row];
    }
    float o0 = 0.f, o1 = 0.f;
    for (int e = e0; e < e1; ++e) {
        int c = cols[e];  // wave-uniform -> broadcast loads
        float a;
        if constexpr (HAS_ALPHA) {
            a = alpha[e];
        } else {
            float v = ev[e] * (s1r + s2[c]);
            v = v > 0.f ? v : LEAKY * v;
            a = __expf(v - mxv) * rsv;
        }
        const MT* mrow = mapped + (size_t)c * CT;
        if (lane < CT) {
            float m0v;
            if constexpr (sizeof(MT) == 4) m0v = ((const float*)mrow)[lane];
            else m0v = bf2f(((const u16*)mrow)[lane]);
            o0 = fmaf(a, m0v, o0);
        }
        if (lane + 64 < CT) {
            float m1v;
            if constexpr (sizeof(MT) == 4) m1v = ((const float*)mrow)[lane + 64];
            else m1v = bf2f(((const u16*)mrow)[lane + 64]);
            o1 = fmaf(a, m1v, o1);
        }
    }
    if (lane < CT) orow[lane] = o0;
    if (lane + 64 < CT) orow[lane + 64] = o1;
}

extern "C" void kernel_launch(void* const* d_in, const int* in_sizes, int n_in,
                              void* d_out, int out_size, void* d_ws, size_t ws_size,
                              hipStream_t stream) {
    const float* x  = (const float*)d_in[0];
    const float* w  = (const float*)d_in[1];
    const float* w1 = (const float*)d_in[2];
    const float* w2 = (const float*)d_in[3];
    const float* ev = (const float*)d_in[4];
    const int* rows = (const int*)d_in[5];
    const int* cols = (const int*)d_in[6];
    float* out = (float*)d_out;

    const int N = in_sizes[0] / D_IN;
    const int E = in_sizes[4];

    // ---- ws layout (adaptive, overflow-proof) ----
    char* base = (char*)d_ws;
    size_t off = 0;
    auto alloc = [&](size_t bytes) -> char* {
        off = (off + 255) & ~(size_t)255;
        char* p = base + off;
        off += bytes;
        return p;
    };
    float* sums  = (float*)alloc(256 * 4);
    float* sqs   = (float*)alloc(256 * 4);
    float* mean  = (float*)alloc(256 * 4);
    float* inv   = (float*)alloc(256 * 4);
    float* s1    = (float*)alloc((size_t)N * 4);
    float* s2    = (float*)alloc((size_t)N * 4);
    float* rmax  = (float*)alloc((size_t)N * 4);
    float* rsm   = (float*)alloc((size_t)N * 4);
    int* row_ptr = (int*)alloc((size_t)(N + 1) * 4);
    size_t head0 = off;

    size_t alpha_bytes = (size_t)E * 4;
    auto fits_alpha = [&](size_t mapped_bytes) {
        size_t o = (head0 + 255) & ~(size_t)255;
        o += alpha_bytes;
        o = (o + 255) & ~(size_t)255;
        return o + mapped_bytes <= ws_size;
    };
    auto fits_noalpha = [&](size_t mapped_bytes) {
        size_t o = (head0 + 255) & ~(size_t)255;
        return o + mapped_bytes <= ws_size;
    };

    bool has_alpha;
    bool map_f32 = false;
    int CT;
    if (fits_alpha((size_t)N * 128 * 4)) {
        has_alpha = true; map_f32 = true; CT = 128;
    } else if (fits_alpha((size_t)N * 128 * 2)) {
        has_alpha = true; CT = 128;
    } else if (fits_alpha((size_t)N * 64 * 2)) {
        has_alpha = true; CT = 64;
    } else if (fits_noalpha((size_t)N * 32 * 2)) {
        has_alpha = false; CT = 32;
    } else if (fits_noalpha((size_t)N * 16 * 2)) {
        has_alpha = false; CT = 16;
    } else {
        has_alpha = false; CT = 8;
    }
    float* alpha = has_alpha ? (float*)alloc(alpha_bytes) : nullptr;
    void* mapped = (void*)alloc((size_t)N * CT * (map_f32 ? 4 : 2));

    // ---- pipeline ----
    hipMemsetAsync(sums, 0, 512 * sizeof(float), stream);
    colstats_k<<<512, 256, 0, stream>>>(x, N, sums, sqs);
    finalize_k<<<1, 256, 0, stream>>>(sums, sqs, N, mean, inv);

    int gb = (N + 63) / 64;
    gemm_quad_k<<<gb, 256, 0, stream>>>(x, w1, mean, inv, s1, N);
    gemm_quad_k<<<gb, 256, 0, stream>>>(x, w2, mean, inv, s2, N);

    build_rowptr_k<<<(E + 255) / 256, 256, 0, stream>>>(rows, E, N, row_ptr);
    int ab = (N + 3) / 4;
    if (has_alpha) {
        row_softmax_k<true><<<ab, 256, 0, stream>>>(row_ptr, cols, ev, s1, s2,
                                                    rmax, rsm, alpha, N);
    } else {
        row_softmax_k<false><<<ab, 256, 0, stream>>>(row_ptr, cols, ev, s1, s2,
                                                     rmax, rsm, nullptr, N);
    }

    for (int c0 = 0; c0 < D_OUT; c0 += CT) {
        if (map_f32) {
            gemm_map_k<float><<<gb, 256, 0, stream>>>(x, w, mean, inv,
                                                      (float*)mapped, N, c0, CT);
            attn_gather_k<float, true><<<ab, 256, 0, stream>>>(
                row_ptr, cols, alpha, ev, s1, s2, rmax, rsm,
                (const float*)mapped, out, N, c0, CT);
        } else {
            gemm_map_k<u16><<<gb, 256, 0, stream>>>(x, w, mean, inv,
                                                    (u16*)mapped, N, c0, CT);
            if (has_alpha) {
                attn_gather_k<u16, true><<<ab, 256, 0, stream>>>(
                    row_ptr, cols, alpha, ev, s1, s2, rmax, rsm,
                    (const u16*)mapped, out, N, c0, CT);
            } else {
                attn_gather_k<u16, false><<<ab, 256, 0, stream>>>(
                    row_ptr, cols, alpha, ev, s1, s2, rmax, rsm,
                    (const u16*)mapped, out, N, c0, CT);
            }
        }
    }
}